// Round 3
// baseline (1922.807 us; speedup 1.0000x reference)
//
#include <hip/hip_runtime.h>
#include <hip/hip_fp16.h>
#include <stdint.h>

#define SEQ   1024
#define BATCH 128
#define INDIM 256
#define HID   512
#define INV_TAU 0.1f

typedef _Float16 f16;
typedef _Float16 f16x2 __attribute__((ext_vector_type(2)));
typedef _Float16 f16x8 __attribute__((ext_vector_type(8)));
typedef float    f32x4 __attribute__((ext_vector_type(4)));

static __device__ __forceinline__ f16x2 pk2(float a, float b) {
  auto r = __builtin_amdgcn_cvt_pkrtz(a, b);
  union { decltype(r) i; f16x2 o; } u;
  u.i = r;
  return u.o;
}

// ---------------------------------------------------------------------------
// K1: A = x @ win + bias  -> written into d_out (in place; K2 overwrites with h)
// ---------------------------------------------------------------------------
__global__ __launch_bounds__(512, 2)
void k1_gemm(const float* __restrict__ x, const float* __restrict__ win,
             const float* __restrict__ bias, float* __restrict__ out) {
  __shared__ __align__(16) f16x2 b_lds[HID][20];

  const int tid  = threadIdx.x;
  const int lane = tid & 63;
  const int wid  = tid >> 6;
  const int wr2  = wid >> 2;
  const int wc   = wid & 3;
  const int l15  = lane & 15;
  const int kg   = lane >> 4;

  const long m0 = (long)blockIdx.x * 64;

  f32x4 acc[2][8];
  #pragma unroll
  for (int a = 0; a < 2; ++a)
    #pragma unroll
    for (int bq = 0; bq < 8; ++bq) acc[a][bq] = (f32x4){0.f, 0.f, 0.f, 0.f};

  const int sp0 = (tid >> 8) * 8;
  const int sn0 = tid & 255;

  for (int ks = 0; ks < 8; ++ks) {
    const int k0 = ks * 32;
    #pragma unroll
    for (int r = 0; r < 8; ++r) {
      const int p = sp0 + r;
      #pragma unroll
      for (int i = 0; i < 2; ++i) {
        const int n = sn0 + 256 * i;
        const float lo = win[(k0 + 2 * p) * HID + n];
        const float hi = win[(k0 + 2 * p + 1) * HID + n];
        const int g  = p >> 2;
        const int gs = g ^ (n & 3);
        b_lds[n][gs * 4 + (p & 3)] = pk2(lo, hi);
      }
    }
    __syncthreads();

    f16x8 af[2];
    #pragma unroll
    for (int mf = 0; mf < 2; ++mf) {
      const long row = m0 + wr2 * 32 + mf * 16 + l15;
      const float4* xp = (const float4*)(x + row * INDIM + k0 + kg * 8);
      const float4 a0 = xp[0];
      const float4 a1 = xp[1];
      union { f16x2 h2[4]; f16x8 h8; } u;
      u.h2[0] = pk2(a0.x, a0.y); u.h2[1] = pk2(a0.z, a0.w);
      u.h2[2] = pk2(a1.x, a1.y); u.h2[3] = pk2(a1.z, a1.w);
      af[mf] = u.h8;
    }

    #pragma unroll
    for (int nf = 0; nf < 8; ++nf) {
      const int n  = wc * 128 + nf * 16 + l15;
      const int gs = kg ^ (n & 3);
      union { uint4 v; f16x8 h8; } u;
      u.v = *(const uint4*)&b_lds[n][gs * 4];
      #pragma unroll
      for (int mf = 0; mf < 2; ++mf)
        acc[mf][nf] = __builtin_amdgcn_mfma_f32_16x16x32_f16(af[mf], u.h8, acc[mf][nf], 0, 0, 0);
    }
    __syncthreads();
  }

  #pragma unroll
  for (int nf = 0; nf < 8; ++nf) {
    const int col = wc * 128 + nf * 16 + l15;
    const float bc = bias[col];
    #pragma unroll
    for (int mf = 0; mf < 2; ++mf) {
      const long rowb = m0 + wr2 * 32 + mf * 16 + kg * 4;
      #pragma unroll
      for (int r = 0; r < 4; ++r)
        out[(rowb + r) * HID + col] = acc[mf][nf][r] + bc;
    }
  }
}

// ---------------------------------------------------------------------------
// K2: per-batch-row recurrence. 128 blocks x 512 threads, 1 block/CU.
//
// *** amdgpu_waves_per_eu(2,2) is load-bearing. ***  Rounds 0-2 all showed
// VGPR_Count=128: launch_bounds' 2nd arg only CAPS registers (min-waves is a
// lower occupancy bound); the allocator's own heuristic targeted 4 waves/EU
// (it cannot see the 149.5KB *dynamic* LDS that already limits the CU to
// 1 block = 2 waves/EU) and spilled ALL 192 weight regs (WRITE_SIZE excess
// = 48MB = 192 regs x 4B x 65536 thr; per-step scratch reloads ~2500cy).
// waves_per_eu(2,2) pins the target: budget 256, need ~237 -> no spill.
//
// Column ownership c = tid (thread computes cols 4jj+m, keeps m=q):
//  - h-store byte addr = 2*tid: lane-consecutive, 32 banks -> conflict-free
//    (old j=jj+128q layout: 256q === 0 mod 128B -> 8-way write conflict every
//    step = the stubborn 8.7M SQ_LDS_BANK_CONFLICT).
//  - out[] store / A[t+1] prefetch load: perfectly coalesced (was 4x64B).
// hbuf content is still h[k] at index k -> all read paths unchanged.
//
// Weights k in [0,384): 192 NAMED f16x2 regs (W0..W47 x 4 cols).
// Weights k in [384,512): 128KB LDS, plane-major self-owned slots
// w4[(gi*4+m)*512+tid] (lane-consecutive b128 reads, conflict-free).
// h f16 double-buffered in LDS, broadcast reads.  1 barrier per step.
// ---------------------------------------------------------------------------
#define K2_SMEM (131072 + 16384 + 2048)

#define DECL_W(u) f16x2 W##u##_0, W##u##_1, W##u##_2, W##u##_3;

#define INIT_U(u) { \
    _Pragma("unroll") \
    for (int r = 0; r < 8; ++r) { \
      const int k = (r >> 1) * 96 + 2 * (u) + (r & 1); \
      slab[r][tid] = wr[k * HID + tid]; \
    } \
    __syncthreads(); \
    W##u##_0 = pk2(slab[2*q][c4    ], slab[2*q+1][c4    ]); \
    W##u##_1 = pk2(slab[2*q][c4 + 1], slab[2*q+1][c4 + 1]); \
    W##u##_2 = pk2(slab[2*q][c4 + 2], slab[2*q+1][c4 + 2]); \
    W##u##_3 = pk2(slab[2*q][c4 + 3], slab[2*q+1][c4 + 3]); \
    __syncthreads(); }

#define FMA_U(u, i) { const f16x2 hh_##u = hu.h2[i]; \
    a0 = __builtin_elementwise_fma(hh_##u, W##u##_0, a0); \
    a1 = __builtin_elementwise_fma(hh_##u, W##u##_1, a1); \
    a2 = __builtin_elementwise_fma(hh_##u, W##u##_2, a2); \
    a3 = __builtin_elementwise_fma(hh_##u, W##u##_3, a3); }

#define GROUP(U, u0,u1,u2,u3) { \
    union { uint4 v; f16x2 h2[4]; } hu; \
    hu.v = *(const uint4*)&hb[q * 48 + (U) * 4]; \
    FMA_U(u0,0) FMA_U(u1,1) FMA_U(u2,2) FMA_U(u3,3) }

__global__ __launch_bounds__(512)
__attribute__((amdgpu_waves_per_eu(2, 2)))
void k2_rnn(const float* __restrict__ wr, float* __restrict__ out) {
  extern __shared__ char smem[];
  uint4* w4          = (uint4*)smem;                               // 8192 uint4 = 128KB
  float (*slab)[HID] = (float(*)[HID])(smem + 131072);             // 8 x 512 fp32 = 16KB
  f16x2 (*hbuf)[256] = (f16x2(*)[256])(smem + 131072 + 16384);     // 2 x 256 pairs = 2KB

  const int tid = threadIdx.x;
  const int q   = tid & 3;
  const int jj  = tid >> 2;
  const int c4  = jj * 4;
  const int b   = blockIdx.x;

  DECL_W(0)  DECL_W(1)  DECL_W(2)  DECL_W(3)  DECL_W(4)  DECL_W(5)
  DECL_W(6)  DECL_W(7)  DECL_W(8)  DECL_W(9)  DECL_W(10) DECL_W(11)
  DECL_W(12) DECL_W(13) DECL_W(14) DECL_W(15) DECL_W(16) DECL_W(17)
  DECL_W(18) DECL_W(19) DECL_W(20) DECL_W(21) DECL_W(22) DECL_W(23)
  DECL_W(24) DECL_W(25) DECL_W(26) DECL_W(27) DECL_W(28) DECL_W(29)
  DECL_W(30) DECL_W(31) DECL_W(32) DECL_W(33) DECL_W(34) DECL_W(35)
  DECL_W(36) DECL_W(37) DECL_W(38) DECL_W(39) DECL_W(40) DECL_W(41)
  DECL_W(42) DECL_W(43) DECL_W(44) DECL_W(45) DECL_W(46) DECL_W(47)

  // ---- LDS weight cache, k in [384,512): plane-major, self-owned slots.
  // w4[(gi*4+m)*512 + tid] = 4 k-pairs (k = 384+32q+8gi ..) of column 4jj+m.
  // Thread reads back its own slots -> no barrier, lane-consecutive b128.
  #pragma unroll
  for (int gi = 0; gi < 4; ++gi) {
    #pragma unroll
    for (int m = 0; m < 4; ++m) {
      const int col = c4 + m;
      const int kb  = 384 + 32 * q + 8 * gi;
      union { uint4 v; f16x2 h2[4]; } u;
      #pragma unroll
      for (int i = 0; i < 4; ++i)
        u.h2[i] = pk2(wr[(long)(kb + 2 * i) * HID + col],
                      wr[(long)(kb + 2 * i + 1) * HID + col]);
      w4[(gi * 4 + m) * 512 + tid] = u.v;
    }
  }

  INIT_U(0)  INIT_U(1)  INIT_U(2)  INIT_U(3)  INIT_U(4)  INIT_U(5)
  INIT_U(6)  INIT_U(7)  INIT_U(8)  INIT_U(9)  INIT_U(10) INIT_U(11)
  INIT_U(12) INIT_U(13) INIT_U(14) INIT_U(15) INIT_U(16) INIT_U(17)
  INIT_U(18) INIT_U(19) INIT_U(20) INIT_U(21) INIT_U(22) INIT_U(23)
  INIT_U(24) INIT_U(25) INIT_U(26) INIT_U(27) INIT_U(28) INIT_U(29)
  INIT_U(30) INIT_U(31) INIT_U(32) INIT_U(33) INIT_U(34) INIT_U(35)
  INIT_U(36) INIT_U(37) INIT_U(38) INIT_U(39) INIT_U(40) INIT_U(41)
  INIT_U(42) INIT_U(43) INIT_U(44) INIT_U(45) INIT_U(46) INIT_U(47)

  const f16x2 Z2 = {(f16)0.f, (f16)0.f};
  if (tid < 256) { hbuf[0][tid] = Z2; hbuf[1][tid] = Z2; }
  __syncthreads();

  const int c = tid;                   // owned output column (coalesced)
  float h = 0.0f;

  float av = out[(long)b * HID + c];   // A[0] prefetch

  const uint4* w4t = w4 + tid;

  #pragma unroll 1
  for (int t = 0; t < SEQ; ++t) {
    const int cur = t & 1;
    const int nxt = cur ^ 1;
    const long aofs = ((long)t * BATCH + b) * HID;
    const int tn = (t + 1 < SEQ) ? (t + 1) : (SEQ - 1);
    const float av_next = out[((long)tn * BATCH + b) * HID + c];

    const f16x2* hb = hbuf[cur];
    f16x2 a0 = Z2, a1 = Z2, a2 = Z2, a3 = Z2;

    // register-weight part: k in [96q, 96q+96), straight-line
    GROUP(0,  0, 1, 2, 3)   GROUP(1,  4, 5, 6, 7)
    GROUP(2,  8, 9,10,11)   GROUP(3, 12,13,14,15)
    GROUP(4, 16,17,18,19)   GROUP(5, 20,21,22,23)
    GROUP(6, 24,25,26,27)   GROUP(7, 28,29,30,31)
    GROUP(8, 32,33,34,35)   GROUP(9, 36,37,38,39)
    GROUP(10,40,41,42,43)   GROUP(11,44,45,46,47)

    // LDS-weight part: k in [384+32q, 384+32q+32), conflict-free self-reads
    #pragma unroll
    for (int gi = 0; gi < 4; ++gi) {
      union { uint4 v; f16x2 h2[4]; } hu;
      hu.v = *(const uint4*)&hb[192 + q * 16 + gi * 4];
      union { uint4 v; f16x2 h2[4]; } w0, w1, w2, w3;
      w0.v = w4t[(gi * 4 + 0) * 512];
      w1.v = w4t[(gi * 4 + 1) * 512];
      w2.v = w4t[(gi * 4 + 2) * 512];
      w3.v = w4t[(gi * 4 + 3) * 512];
      #pragma unroll
      for (int i = 0; i < 4; ++i) {
        const f16x2 hh = hu.h2[i];
        a0 = __builtin_elementwise_fma(hh, w0.h2[i], a0);
        a1 = __builtin_elementwise_fma(hh, w1.h2[i], a1);
        a2 = __builtin_elementwise_fma(hh, w2.h2[i], a2);
        a3 = __builtin_elementwise_fma(hh, w3.h2[i], a3);
      }
    }

    // reduce the 4 k-slices (a_m = partials for column 4jj+m)
    float y0 = (float)a0[0] + (float)a0[1];
    float y1 = (float)a1[0] + (float)a1[1];
    float y2 = (float)a2[0] + (float)a2[1];
    float y3 = (float)a3[0] + (float)a3[1];
    y0 += __shfl_xor(y0, 1); y0 += __shfl_xor(y0, 2);
    y1 += __shfl_xor(y1, 1); y1 += __shfl_xor(y1, 2);
    y2 += __shfl_xor(y2, 1); y2 += __shfl_xor(y2, 2);
    y3 += __shfl_xor(y3, 1); y3 += __shfl_xor(y3, 2);
    const float y = (q == 0) ? y0 : (q == 1) ? y1 : (q == 2) ? y2 : y3;

    // leaky update: h += 0.1*(tanh(A + y) - h)
    const float arg = av + y;
    const float e  = __expf(2.0f * arg);
    const float th = 1.0f - 2.0f / (e + 1.0f);
    h += INV_TAU * (th - h);

    out[aofs + c] = h;                        // coalesced
    ((f16*)hbuf[nxt])[c] = (f16)h;            // byte 2*tid: conflict-free
    av = av_next;
    __syncthreads();
  }
}

// ---------------------------------------------------------------------------
extern "C" void kernel_launch(void* const* d_in, const int* in_sizes, int n_in,
                              void* d_out, int out_size, void* d_ws, size_t ws_size,
                              hipStream_t stream) {
  const float* x    = (const float*)d_in[0];
  const float* win  = (const float*)d_in[1];
  const float* wr   = (const float*)d_in[2];
  const float* bias = (const float*)d_in[3];
  float* out = (float*)d_out;

  (void)d_ws; (void)ws_size; (void)in_sizes; (void)n_in; (void)out_size;

  (void)hipFuncSetAttribute((const void*)k2_rnn,
                            hipFuncAttributeMaxDynamicSharedMemorySize, K2_SMEM);

  k1_gemm<<<dim3((SEQ * BATCH) / 64), dim3(512), 0, stream>>>(x, win, bias, out);
  k2_rnn<<<dim3(BATCH), dim3(512), K2_SMEM, stream>>>(wr, out);
}